// Round 1
// baseline (2527.514 us; speedup 1.0000x reference)
//
#include <hip/hip_runtime.h>
#include <math.h>

// ---------------------------------------------------------------------------
// AdvancedGCN on MI355X — round 1: correct f32 baseline.
// Pipeline per layer: GEMM(h=x@W, agg=h*dinv^2+b) -> edge scatter (atomics)
//                     -> BN+ReLU+residual. Then fused classifier+log_softmax.
// ---------------------------------------------------------------------------

#define BN_EPS 1e-5f

// ----------------------------- degree kernels ------------------------------
__global__ void deg_init_kernel(float* __restrict__ deg, int N) {
    int n = blockIdx.x * 256 + threadIdx.x;
    if (n < N) deg[n] = 1.0f;   // self loop
}

__global__ void deg_count_kernel(const int* __restrict__ dst, float* __restrict__ deg, int E) {
    int e = blockIdx.x * 256 + threadIdx.x;
    if (e < E) unsafeAtomicAdd(&deg[dst[e]], 1.0f);
}

__global__ void deg_rsqrt_kernel(float* __restrict__ deg, int N) {
    int n = blockIdx.x * 256 + threadIdx.x;
    if (n < N) deg[n] = rsqrtf(deg[n]);   // deg >= 1
}

// ------------------------------- GEMM -------------------------------------
// h = X[N,K] @ W[K,M].  CONV epilogue also writes AGG = h*dinv[n]^2 + bias
// (GCN self-loop message + bias), so AGG needs no memset.
// Thread block: 256 threads; each thread computes RT=4 rows x CT=8 cols.
template <int K, int M, bool CONV>
__launch_bounds__(256)
__global__ void gemm_kernel(const float* __restrict__ X, const float* __restrict__ W,
                            const float* __restrict__ bias, const float* __restrict__ dinv,
                            float* __restrict__ H, float* __restrict__ AGG, int N)
{
    constexpr int CT   = 8;
    constexpr int COLT = M / CT;        // 16 / 8 / 4
    constexpr int RT   = 4;
    constexpr int TR   = (256 / COLT) * RT;  // 64 / 128 / 256 rows per block
    constexpr int KC   = 32;
    constexpr int PADW = 4;

    __shared__ float Xs[KC][TR];        // transposed: Xs[k][row]
    __shared__ float Ws[KC][M + PADW];

    const int tid = threadIdx.x;
    const int i = tid / COLT;           // row-group id
    const int j = tid % COLT;           // col-group id
    const int r0 = blockIdx.x * TR;

    float acc[RT][CT];
#pragma unroll
    for (int r = 0; r < RT; ++r)
#pragma unroll
        for (int c = 0; c < CT; ++c) acc[r][c] = 0.0f;

    for (int k0 = 0; k0 < K; k0 += KC) {
        __syncthreads();
        // stage X tile (TR x KC), transposed into LDS
#pragma unroll
        for (int l = 0; l < TR / 32; ++l) {
            int f   = tid + 256 * l;
            int row = f >> 3;           // KC/4 == 8 float4 per row
            int kq  = f & 7;
            float4 v = make_float4(0.f, 0.f, 0.f, 0.f);
            if (r0 + row < N)
                v = *(const float4*)&X[(size_t)(r0 + row) * K + k0 + kq * 4];
            Xs[kq * 4 + 0][row] = v.x;
            Xs[kq * 4 + 1][row] = v.y;
            Xs[kq * 4 + 2][row] = v.z;
            Xs[kq * 4 + 3][row] = v.w;
        }
        // stage W tile (KC x M)
#pragma unroll
        for (int l = 0; l < M / 32; ++l) {
            int f  = tid + 256 * l;
            int kr = f / (M / 4);
            int mq = f % (M / 4);
            *(float4*)&Ws[kr][mq * 4] = *(const float4*)&W[(size_t)(k0 + kr) * M + mq * 4];
        }
        __syncthreads();

#pragma unroll
        for (int kc = 0; kc < KC; ++kc) {
            float4 xa = *(const float4*)&Xs[kc][i * RT];
            float4 w0 = *(const float4*)&Ws[kc][j * CT];
            float4 w1 = *(const float4*)&Ws[kc][j * CT + 4];
            float xr[RT] = {xa.x, xa.y, xa.z, xa.w};
            float wc[CT] = {w0.x, w0.y, w0.z, w0.w, w1.x, w1.y, w1.z, w1.w};
#pragma unroll
            for (int r = 0; r < RT; ++r)
#pragma unroll
                for (int c = 0; c < CT; ++c)
                    acc[r][c] = fmaf(xr[r], wc[c], acc[r][c]);
        }
    }

    const float4 bv0 = *(const float4*)&bias[j * CT];
    const float4 bv1 = *(const float4*)&bias[j * CT + 4];
#pragma unroll
    for (int r = 0; r < RT; ++r) {
        int row = r0 + i * RT + r;
        if (row >= N) continue;
        size_t base = (size_t)row * M + j * CT;
        float4 h0 = make_float4(acc[r][0], acc[r][1], acc[r][2], acc[r][3]);
        float4 h1 = make_float4(acc[r][4], acc[r][5], acc[r][6], acc[r][7]);
        if constexpr (CONV) {
            *(float4*)&H[base]     = h0;
            *(float4*)&H[base + 4] = h1;
            float d  = dinv[row];
            float d2 = d * d;
            float4 a0 = make_float4(fmaf(h0.x, d2, bv0.x), fmaf(h0.y, d2, bv0.y),
                                    fmaf(h0.z, d2, bv0.z), fmaf(h0.w, d2, bv0.w));
            float4 a1 = make_float4(fmaf(h1.x, d2, bv1.x), fmaf(h1.y, d2, bv1.y),
                                    fmaf(h1.z, d2, bv1.z), fmaf(h1.w, d2, bv1.w));
            *(float4*)&AGG[base]     = a0;
            *(float4*)&AGG[base + 4] = a1;
        } else {
            float4 s0 = make_float4(h0.x + bv0.x, h0.y + bv0.y, h0.z + bv0.z, h0.w + bv0.w);
            float4 s1 = make_float4(h1.x + bv1.x, h1.y + bv1.y, h1.z + bv1.z, h1.w + bv1.w);
            *(float4*)&H[base]     = s0;
            *(float4*)&H[base + 4] = s1;
        }
    }
}

// ---------------------------- edge scatter ---------------------------------
// AGG[dst] += H[src] * dinv[src]*dinv[dst], one (edge, float4-chunk) per thread.
template <int M>
__global__ void scatter_kernel(const int* __restrict__ src, const int* __restrict__ dst,
                               const float* __restrict__ dinv,
                               const float* __restrict__ H, float* __restrict__ AGG, int E)
{
    constexpr int C4 = M / 4;
    int idx = blockIdx.x * 256 + threadIdx.x;
    if (idx >= E * C4) return;
    int e = idx / C4;
    int c = idx % C4;
    int s = src[e];
    int d = dst[e];
    float w = dinv[s] * dinv[d];
    float4 h = *(const float4*)&H[(size_t)s * M + c * 4];
    float* a = &AGG[(size_t)d * M + c * 4];
    unsafeAtomicAdd(a + 0, h.x * w);
    unsafeAtomicAdd(a + 1, h.y * w);
    unsafeAtomicAdd(a + 2, h.z * w);
    unsafeAtomicAdd(a + 3, h.w * w);
}

// --------------------- BN + ReLU + residual (fused) ------------------------
template <int M>
__global__ void bnrelu_kernel(const float* __restrict__ AGG,
                              const float* __restrict__ g, const float* __restrict__ b,
                              const float* __restrict__ m, const float* __restrict__ v,
                              const float* __restrict__ res, float* __restrict__ out, int N)
{
    constexpr int C4 = M / 4;
    int idx = blockIdx.x * 256 + threadIdx.x;
    if (idx >= N * C4) return;
    int c = (idx % C4) * 4;
    float4 av = *(const float4*)&AGG[(size_t)idx * 4];
    float4 gv = *(const float4*)&g[c];
    float4 bv = *(const float4*)&b[c];
    float4 mv = *(const float4*)&m[c];
    float4 vv = *(const float4*)&v[c];
    float4 rv = *(const float4*)&res[(size_t)idx * 4];
    float4 o;
    o.x = fmaxf((av.x - mv.x) * rsqrtf(vv.x + BN_EPS) * gv.x + bv.x, 0.f) + rv.x;
    o.y = fmaxf((av.y - mv.y) * rsqrtf(vv.y + BN_EPS) * gv.y + bv.y, 0.f) + rv.y;
    o.z = fmaxf((av.z - mv.z) * rsqrtf(vv.z + BN_EPS) * gv.z + bv.z, 0.f) + rv.z;
    o.w = fmaxf((av.w - mv.w) * rsqrtf(vv.w + BN_EPS) * gv.w + bv.w, 0.f) + rv.w;
    *(float4*)&out[(size_t)idx * 4] = o;
}

// ------------------------- classifier + log_softmax ------------------------
__global__ void classifier_kernel(const float* __restrict__ H2,
                                  const float* __restrict__ W1, const float* __restrict__ B1,
                                  const float* __restrict__ W2, const float* __restrict__ B2,
                                  float* __restrict__ out, int N)
{
    __shared__ float w1s[32 * 16];
    __shared__ float b1s[16];
    __shared__ float w2s[16 * 2];
    __shared__ float b2s[2];
    int tid = threadIdx.x;
    for (int t = tid; t < 512; t += 256) w1s[t] = W1[t];
    if (tid < 16) b1s[tid] = B1[tid];
    if (tid < 32) w2s[tid] = W2[tid];
    if (tid < 2)  b2s[tid] = B2[tid];
    __syncthreads();

    int n = blockIdx.x * 256 + tid;
    if (n >= N) return;

    float x[32];
#pragma unroll
    for (int q = 0; q < 8; ++q) {
        float4 v = *(const float4*)&H2[(size_t)n * 32 + q * 4];
        x[q * 4 + 0] = v.x; x[q * 4 + 1] = v.y; x[q * 4 + 2] = v.z; x[q * 4 + 3] = v.w;
    }
    float h[16];
#pragma unroll
    for (int jj = 0; jj < 16; ++jj) h[jj] = b1s[jj];
#pragma unroll
    for (int k = 0; k < 32; ++k)
#pragma unroll
        for (int jj = 0; jj < 16; ++jj)
            h[jj] = fmaf(x[k], w1s[k * 16 + jj], h[jj]);

    float z0 = b2s[0], z1 = b2s[1];
#pragma unroll
    for (int jj = 0; jj < 16; ++jj) {
        float r = fmaxf(h[jj], 0.f);
        z0 = fmaf(r, w2s[jj * 2 + 0], z0);
        z1 = fmaf(r, w2s[jj * 2 + 1], z1);
    }
    float mx  = fmaxf(z0, z1);
    float lse = mx + logf(expf(z0 - mx) + expf(z1 - mx));
    out[(size_t)n * 2 + 0] = z0 - lse;
    out[(size_t)n * 2 + 1] = z1 - lse;
}

// ------------------------------- launch ------------------------------------
extern "C" void kernel_launch(void* const* d_in, const int* in_sizes, int n_in,
                              void* d_out, int out_size, void* d_ws, size_t ws_size,
                              hipStream_t stream)
{
    const float* x      = (const float*)d_in[0];
    const int*   edge   = (const int*)d_in[1];
    const float* W0     = (const float*)d_in[2];
    const float* b0v    = (const float*)d_in[3];
    const float* bn0g   = (const float*)d_in[4];
    const float* bn0b   = (const float*)d_in[5];
    const float* bn0m   = (const float*)d_in[6];
    const float* bn0v   = (const float*)d_in[7];
    const float* W1     = (const float*)d_in[8];
    const float* b1v    = (const float*)d_in[9];
    const float* bn1g   = (const float*)d_in[10];
    const float* bn1b   = (const float*)d_in[11];
    const float* bn1m   = (const float*)d_in[12];
    const float* bn1v   = (const float*)d_in[13];
    const float* sk1W   = (const float*)d_in[14];
    const float* sk1b   = (const float*)d_in[15];
    const float* W2     = (const float*)d_in[16];
    const float* b2v    = (const float*)d_in[17];
    const float* bn2g   = (const float*)d_in[18];
    const float* bn2b   = (const float*)d_in[19];
    const float* bn2m   = (const float*)d_in[20];
    const float* bn2v   = (const float*)d_in[21];
    const float* sk2W   = (const float*)d_in[22];
    const float* sk2b   = (const float*)d_in[23];
    const float* c1W    = (const float*)d_in[24];
    const float* c1b    = (const float*)d_in[25];
    const float* c2W    = (const float*)d_in[26];
    const float* c2b    = (const float*)d_in[27];

    const int N = in_sizes[0] / 128;
    const int E = in_sizes[1] / 2;
    const int* src = edge;
    const int* dst = edge + E;

    // workspace layout (256B-aligned)
    char*  ws  = (char*)d_ws;
    size_t off = 0;
    auto alloc = [&](size_t bytes) -> float* {
        float* p = (float*)(ws + off);
        off += (bytes + 255) & ~(size_t)255;
        return p;
    };
    float* dinv = alloc((size_t)N * 4);
    float* P    = alloc((size_t)N * 128 * 4);   // h buffer / out1
    float* Q    = alloc((size_t)N * 128 * 4);   // out0 / h2 + out2
    float* AGG  = alloc((size_t)N * 128 * 4);
    float* SK   = alloc((size_t)N * 64 * 4);
    (void)ws_size; (void)n_in; (void)out_size;

    dim3 blk(256);
    auto cdiv = [](int a, int b) { return (a + b - 1) / b; };

    // degrees -> dinv
    deg_init_kernel<<<cdiv(N, 256), blk, 0, stream>>>(dinv, N);
    deg_count_kernel<<<cdiv(E, 256), blk, 0, stream>>>(dst, dinv, E);
    deg_rsqrt_kernel<<<cdiv(N, 256), blk, 0, stream>>>(dinv, N);

    // ---- layer 0: 128 -> 128, residual = x ----
    gemm_kernel<128, 128, true><<<cdiv(N, 64), blk, 0, stream>>>(x, W0, b0v, dinv, P, AGG, N);
    scatter_kernel<128><<<cdiv(E * 32, 256), blk, 0, stream>>>(src, dst, dinv, P, AGG, E);
    bnrelu_kernel<128><<<cdiv(N * 32, 256), blk, 0, stream>>>(AGG, bn0g, bn0b, bn0m, bn0v, x, Q, N);

    // ---- layer 1: 128 -> 64, residual = Q @ sk1W + sk1b ----
    gemm_kernel<128, 64, true><<<cdiv(N, 128), blk, 0, stream>>>(Q, W1, b1v, dinv, P, AGG, N);
    gemm_kernel<128, 64, false><<<cdiv(N, 128), blk, 0, stream>>>(Q, sk1W, sk1b, nullptr, SK, nullptr, N);
    scatter_kernel<64><<<cdiv(E * 16, 256), blk, 0, stream>>>(src, dst, dinv, P, AGG, E);
    bnrelu_kernel<64><<<cdiv(N * 16, 256), blk, 0, stream>>>(AGG, bn1g, bn1b, bn1m, bn1v, SK, P, N);

    // ---- layer 2: 64 -> 32, residual = P @ sk2W + sk2b ----
    gemm_kernel<64, 32, true><<<cdiv(N, 256), blk, 0, stream>>>(P, W2, b2v, dinv, Q, AGG, N);
    gemm_kernel<64, 32, false><<<cdiv(N, 256), blk, 0, stream>>>(P, sk2W, sk2b, nullptr, SK, nullptr, N);
    scatter_kernel<32><<<cdiv(E * 8, 256), blk, 0, stream>>>(src, dst, dinv, Q, AGG, E);
    float* OUT2 = Q + (size_t)N * 32;
    bnrelu_kernel<32><<<cdiv(N * 8, 256), blk, 0, stream>>>(AGG, bn2g, bn2b, bn2m, bn2v, SK, OUT2, N);

    // ---- classifier + log_softmax ----
    classifier_kernel<<<cdiv(N, 256), blk, 0, stream>>>(OUT2, c1W, c1b, c2W, c2b, (float*)d_out, N);
}

// Round 2
// 346.879 us; speedup vs baseline: 7.2864x; 7.2864x over previous
//
#include <hip/hip_runtime.h>
#include <math.h>

// ---------------------------------------------------------------------------
// AdvancedGCN on MI355X — round 2: replace atomic scatter with CSR gather.
// CSR (by dst) built on-device each call: histogram -> scan -> bucket fill.
// Aggregation = per-node register gather, no atomics in the hot path.
// ---------------------------------------------------------------------------

#define BN_EPS 1e-5f

// --------------------------- CSR build kernels -----------------------------
__global__ void zero_counts_kernel(int* __restrict__ counts, int N) {
    int i = blockIdx.x * 256 + threadIdx.x;
    if (i < N) counts[i] = 0;
}

__global__ void hist_kernel(const int* __restrict__ dst, int* __restrict__ counts, int E) {
    int e = blockIdx.x * 256 + threadIdx.x;
    if (e < E) atomicAdd(&counts[dst[e]], 1);
}

// block-level inclusive scan -> per-element exclusive + block sums
__global__ void scan_block_kernel(const int* __restrict__ counts, int* __restrict__ excl,
                                  int* __restrict__ bsum, int N) {
    __shared__ int s[256];
    int tid = threadIdx.x;
    int i = blockIdx.x * 256 + tid;
    int v = (i < N) ? counts[i] : 0;
    s[tid] = v;
    __syncthreads();
#pragma unroll
    for (int off = 1; off < 256; off <<= 1) {
        int t = (tid >= off) ? s[tid - off] : 0;
        __syncthreads();
        s[tid] += t;
        __syncthreads();
    }
    if (i < N) excl[i] = s[tid] - v;
    if (tid == 255) bsum[blockIdx.x] = s[255];
}

// single-block scan of block sums (nb <= 256)
__global__ void scan_sums_kernel(const int* __restrict__ bsum, int* __restrict__ boff, int nb) {
    __shared__ int s[256];
    int tid = threadIdx.x;
    int v = (tid < nb) ? bsum[tid] : 0;
    s[tid] = v;
    __syncthreads();
#pragma unroll
    for (int off = 1; off < 256; off <<= 1) {
        int t = (tid >= off) ? s[tid - off] : 0;
        __syncthreads();
        s[tid] += t;
        __syncthreads();
    }
    if (tid < nb) boff[tid] = s[tid] - v;
}

// finalize rowptr/cursor, compute dinv = rsqrt(indeg + 1)
__global__ void scan_add_kernel(const int* __restrict__ excl, const int* __restrict__ boff,
                                const int* __restrict__ counts,
                                int* __restrict__ rowptr, int* __restrict__ cursor,
                                float* __restrict__ dinv, int N, int E) {
    int i = blockIdx.x * 256 + threadIdx.x;
    if (i < N) {
        int val = excl[i] + boff[blockIdx.x];
        rowptr[i] = val;
        cursor[i] = val;
        dinv[i]   = rsqrtf((float)counts[i] + 1.0f);
    }
    if (i == N) rowptr[N] = E;
}

// bucket fill: csr[pos] = {src, bits(dinv[src]*dinv[dst])}
__global__ void build_csr_kernel(const int* __restrict__ src, const int* __restrict__ dst,
                                 const float* __restrict__ dinv, int* __restrict__ cursor,
                                 int2* __restrict__ csr, int E) {
    int e = blockIdx.x * 256 + threadIdx.x;
    if (e >= E) return;
    int s = src[e], d = dst[e];
    int pos = atomicAdd(&cursor[d], 1);
    csr[pos] = make_int2(s, __float_as_int(dinv[s] * dinv[d]));
}

// ------------------------------- GEMM -------------------------------------
// h = X[N,K] @ W[K,M].  CONV epilogue also writes AGG = h*dinv[n]^2 + bias.
template <int K, int M, bool CONV>
__launch_bounds__(256)
__global__ void gemm_kernel(const float* __restrict__ X, const float* __restrict__ W,
                            const float* __restrict__ bias, const float* __restrict__ dinv,
                            float* __restrict__ H, float* __restrict__ AGG, int N)
{
    constexpr int CT   = 8;
    constexpr int COLT = M / CT;
    constexpr int RT   = 4;
    constexpr int TR   = (256 / COLT) * RT;
    constexpr int KC   = 32;
    constexpr int PADW = 4;

    __shared__ float Xs[KC][TR];
    __shared__ float Ws[KC][M + PADW];

    const int tid = threadIdx.x;
    const int i = tid / COLT;
    const int j = tid % COLT;
    const int r0 = blockIdx.x * TR;

    float acc[RT][CT];
#pragma unroll
    for (int r = 0; r < RT; ++r)
#pragma unroll
        for (int c = 0; c < CT; ++c) acc[r][c] = 0.0f;

    for (int k0 = 0; k0 < K; k0 += KC) {
        __syncthreads();
#pragma unroll
        for (int l = 0; l < TR / 32; ++l) {
            int f   = tid + 256 * l;
            int row = f >> 3;
            int kq  = f & 7;
            float4 v = make_float4(0.f, 0.f, 0.f, 0.f);
            if (r0 + row < N)
                v = *(const float4*)&X[(size_t)(r0 + row) * K + k0 + kq * 4];
            Xs[kq * 4 + 0][row] = v.x;
            Xs[kq * 4 + 1][row] = v.y;
            Xs[kq * 4 + 2][row] = v.z;
            Xs[kq * 4 + 3][row] = v.w;
        }
#pragma unroll
        for (int l = 0; l < M / 32; ++l) {
            int f  = tid + 256 * l;
            int kr = f / (M / 4);
            int mq = f % (M / 4);
            *(float4*)&Ws[kr][mq * 4] = *(const float4*)&W[(size_t)(k0 + kr) * M + mq * 4];
        }
        __syncthreads();

#pragma unroll
        for (int kc = 0; kc < KC; ++kc) {
            float4 xa = *(const float4*)&Xs[kc][i * RT];
            float4 w0 = *(const float4*)&Ws[kc][j * CT];
            float4 w1 = *(const float4*)&Ws[kc][j * CT + 4];
            float xr[RT] = {xa.x, xa.y, xa.z, xa.w};
            float wc[CT] = {w0.x, w0.y, w0.z, w0.w, w1.x, w1.y, w1.z, w1.w};
#pragma unroll
            for (int r = 0; r < RT; ++r)
#pragma unroll
                for (int c = 0; c < CT; ++c)
                    acc[r][c] = fmaf(xr[r], wc[c], acc[r][c]);
        }
    }

    const float4 bv0 = *(const float4*)&bias[j * CT];
    const float4 bv1 = *(const float4*)&bias[j * CT + 4];
#pragma unroll
    for (int r = 0; r < RT; ++r) {
        int row = r0 + i * RT + r;
        if (row >= N) continue;
        size_t base = (size_t)row * M + j * CT;
        float4 h0 = make_float4(acc[r][0], acc[r][1], acc[r][2], acc[r][3]);
        float4 h1 = make_float4(acc[r][4], acc[r][5], acc[r][6], acc[r][7]);
        if constexpr (CONV) {
            *(float4*)&H[base]     = h0;
            *(float4*)&H[base + 4] = h1;
            float d  = dinv[row];
            float d2 = d * d;
            float4 a0 = make_float4(fmaf(h0.x, d2, bv0.x), fmaf(h0.y, d2, bv0.y),
                                    fmaf(h0.z, d2, bv0.z), fmaf(h0.w, d2, bv0.w));
            float4 a1 = make_float4(fmaf(h1.x, d2, bv1.x), fmaf(h1.y, d2, bv1.y),
                                    fmaf(h1.z, d2, bv1.z), fmaf(h1.w, d2, bv1.w));
            *(float4*)&AGG[base]     = a0;
            *(float4*)&AGG[base + 4] = a1;
        } else {
            float4 s0 = make_float4(h0.x + bv0.x, h0.y + bv0.y, h0.z + bv0.z, h0.w + bv0.w);
            float4 s1 = make_float4(h1.x + bv1.x, h1.y + bv1.y, h1.z + bv1.z, h1.w + bv1.w);
            *(float4*)&H[base]     = s0;
            *(float4*)&H[base + 4] = s1;
        }
    }
}

// ---------------------------- CSR gather -----------------------------------
// AGG[n] += sum_{p in row n} H[csr[p].src] * csr[p].w
// One node per (M/4)-lane group; each lane owns a float4 column slice.
template <int M>
__launch_bounds__(256)
__global__ void gather_kernel(const int* __restrict__ rowptr, const int2* __restrict__ csr,
                              const float* __restrict__ H, float* __restrict__ AGG, int N)
{
    constexpr int TPN = M / 4;
    int gid = blockIdx.x * 256 + threadIdx.x;
    int n = gid / TPN;
    int c = (gid % TPN) * 4;
    if (n >= N) return;
    int beg = rowptr[n];
    int end = rowptr[n + 1];
    float4 acc = make_float4(0.f, 0.f, 0.f, 0.f);
    for (int p = beg; p < end; ++p) {
        int2 sw = csr[p];
        float w = __int_as_float(sw.y);
        float4 h = *(const float4*)&H[(size_t)sw.x * M + c];
        acc.x = fmaf(h.x, w, acc.x);
        acc.y = fmaf(h.y, w, acc.y);
        acc.z = fmaf(h.z, w, acc.z);
        acc.w = fmaf(h.w, w, acc.w);
    }
    float* ap = &AGG[(size_t)n * M + c];
    float4 a = *(const float4*)ap;
    a.x += acc.x; a.y += acc.y; a.z += acc.z; a.w += acc.w;
    *(float4*)ap = a;
}

// --------------------- BN + ReLU + residual (fused) ------------------------
template <int M>
__global__ void bnrelu_kernel(const float* __restrict__ AGG,
                              const float* __restrict__ g, const float* __restrict__ b,
                              const float* __restrict__ m, const float* __restrict__ v,
                              const float* __restrict__ res, float* __restrict__ out, int N)
{
    constexpr int C4 = M / 4;
    int idx = blockIdx.x * 256 + threadIdx.x;
    if (idx >= N * C4) return;
    int c = (idx % C4) * 4;
    float4 av = *(const float4*)&AGG[(size_t)idx * 4];
    float4 gv = *(const float4*)&g[c];
    float4 bv = *(const float4*)&b[c];
    float4 mv = *(const float4*)&m[c];
    float4 vv = *(const float4*)&v[c];
    float4 rv = *(const float4*)&res[(size_t)idx * 4];
    float4 o;
    o.x = fmaxf((av.x - mv.x) * rsqrtf(vv.x + BN_EPS) * gv.x + bv.x, 0.f) + rv.x;
    o.y = fmaxf((av.y - mv.y) * rsqrtf(vv.y + BN_EPS) * gv.y + bv.y, 0.f) + rv.y;
    o.z = fmaxf((av.z - mv.z) * rsqrtf(vv.z + BN_EPS) * gv.z + bv.z, 0.f) + rv.z;
    o.w = fmaxf((av.w - mv.w) * rsqrtf(vv.w + BN_EPS) * gv.w + bv.w, 0.f) + rv.w;
    *(float4*)&out[(size_t)idx * 4] = o;
}

// ------------------------- classifier + log_softmax ------------------------
__global__ void classifier_kernel(const float* __restrict__ H2,
                                  const float* __restrict__ W1, const float* __restrict__ B1,
                                  const float* __restrict__ W2, const float* __restrict__ B2,
                                  float* __restrict__ out, int N)
{
    __shared__ float w1s[32 * 16];
    __shared__ float b1s[16];
    __shared__ float w2s[16 * 2];
    __shared__ float b2s[2];
    int tid = threadIdx.x;
    for (int t = tid; t < 512; t += 256) w1s[t] = W1[t];
    if (tid < 16) b1s[tid] = B1[tid];
    if (tid < 32) w2s[tid] = W2[tid];
    if (tid < 2)  b2s[tid] = B2[tid];
    __syncthreads();

    int n = blockIdx.x * 256 + tid;
    if (n >= N) return;

    float x[32];
#pragma unroll
    for (int q = 0; q < 8; ++q) {
        float4 v = *(const float4*)&H2[(size_t)n * 32 + q * 4];
        x[q * 4 + 0] = v.x; x[q * 4 + 1] = v.y; x[q * 4 + 2] = v.z; x[q * 4 + 3] = v.w;
    }
    float h[16];
#pragma unroll
    for (int jj = 0; jj < 16; ++jj) h[jj] = b1s[jj];
#pragma unroll
    for (int k = 0; k < 32; ++k)
#pragma unroll
        for (int jj = 0; jj < 16; ++jj)
            h[jj] = fmaf(x[k], w1s[k * 16 + jj], h[jj]);

    float z0 = b2s[0], z1 = b2s[1];
#pragma unroll
    for (int jj = 0; jj < 16; ++jj) {
        float r = fmaxf(h[jj], 0.f);
        z0 = fmaf(r, w2s[jj * 2 + 0], z0);
        z1 = fmaf(r, w2s[jj * 2 + 1], z1);
    }
    float mx  = fmaxf(z0, z1);
    float lse = mx + logf(expf(z0 - mx) + expf(z1 - mx));
    out[(size_t)n * 2 + 0] = z0 - lse;
    out[(size_t)n * 2 + 1] = z1 - lse;
}

// ------------------------------- launch ------------------------------------
extern "C" void kernel_launch(void* const* d_in, const int* in_sizes, int n_in,
                              void* d_out, int out_size, void* d_ws, size_t ws_size,
                              hipStream_t stream)
{
    const float* x      = (const float*)d_in[0];
    const int*   edge   = (const int*)d_in[1];
    const float* W0     = (const float*)d_in[2];
    const float* b0v    = (const float*)d_in[3];
    const float* bn0g   = (const float*)d_in[4];
    const float* bn0b   = (const float*)d_in[5];
    const float* bn0m   = (const float*)d_in[6];
    const float* bn0v   = (const float*)d_in[7];
    const float* W1     = (const float*)d_in[8];
    const float* b1v    = (const float*)d_in[9];
    const float* bn1g   = (const float*)d_in[10];
    const float* bn1b   = (const float*)d_in[11];
    const float* bn1m   = (const float*)d_in[12];
    const float* bn1v   = (const float*)d_in[13];
    const float* sk1W   = (const float*)d_in[14];
    const float* sk1b   = (const float*)d_in[15];
    const float* W2     = (const float*)d_in[16];
    const float* b2v    = (const float*)d_in[17];
    const float* bn2g   = (const float*)d_in[18];
    const float* bn2b   = (const float*)d_in[19];
    const float* bn2m   = (const float*)d_in[20];
    const float* bn2v   = (const float*)d_in[21];
    const float* sk2W   = (const float*)d_in[22];
    const float* sk2b   = (const float*)d_in[23];
    const float* c1W    = (const float*)d_in[24];
    const float* c1b    = (const float*)d_in[25];
    const float* c2W    = (const float*)d_in[26];
    const float* c2b    = (const float*)d_in[27];

    const int N = in_sizes[0] / 128;
    const int E = in_sizes[1] / 2;
    const int* src = edge;
    const int* dst = edge + E;

    // workspace layout (256B-aligned)
    char*  ws  = (char*)d_ws;
    size_t off = 0;
    auto alloc = [&](size_t bytes) -> char* {
        char* p = ws + off;
        off += (bytes + 255) & ~(size_t)255;
        return p;
    };
    float* dinv   = (float*)alloc((size_t)N * 4);
    int*   counts = (int*)  alloc((size_t)N * 4);
    int*   excl   = (int*)  alloc((size_t)N * 4);
    int*   rowptr = (int*)  alloc((size_t)(N + 1) * 4);
    int*   cursor = (int*)  alloc((size_t)N * 4);
    int*   bsum   = (int*)  alloc(256 * 4);
    int*   boff   = (int*)  alloc(256 * 4);
    int2*  csr    = (int2*) alloc((size_t)E * 8);
    float* P      = (float*)alloc((size_t)N * 128 * 4);
    float* Q      = (float*)alloc((size_t)N * 128 * 4);
    float* AGG    = (float*)alloc((size_t)N * 128 * 4);
    float* SK     = (float*)alloc((size_t)N * 64 * 4);
    (void)ws_size; (void)n_in; (void)out_size;

    dim3 blk(256);
    auto cdiv = [](int a, int b) { return (a + b - 1) / b; };
    const int nbN = cdiv(N, 256);

    // ---- CSR build (by dst) + dinv ----
    zero_counts_kernel<<<nbN, blk, 0, stream>>>(counts, N);
    hist_kernel<<<cdiv(E, 256), blk, 0, stream>>>(dst, counts, E);
    scan_block_kernel<<<nbN, blk, 0, stream>>>(counts, excl, bsum, N);
    scan_sums_kernel<<<1, blk, 0, stream>>>(bsum, boff, nbN);
    scan_add_kernel<<<cdiv(N + 1, 256), blk, 0, stream>>>(excl, boff, counts, rowptr, cursor, dinv, N, E);
    build_csr_kernel<<<cdiv(E, 256), blk, 0, stream>>>(src, dst, dinv, cursor, csr, E);

    // ---- layer 0: 128 -> 128, residual = x ----
    gemm_kernel<128, 128, true><<<cdiv(N, 64), blk, 0, stream>>>(x, W0, b0v, dinv, P, AGG, N);
    gather_kernel<128><<<cdiv(N * 32, 256), blk, 0, stream>>>(rowptr, csr, P, AGG, N);
    bnrelu_kernel<128><<<cdiv(N * 32, 256), blk, 0, stream>>>(AGG, bn0g, bn0b, bn0m, bn0v, x, Q, N);

    // ---- layer 1: 128 -> 64, residual = Q @ sk1W + sk1b ----
    gemm_kernel<128, 64, true><<<cdiv(N, 128), blk, 0, stream>>>(Q, W1, b1v, dinv, P, AGG, N);
    gemm_kernel<128, 64, false><<<cdiv(N, 128), blk, 0, stream>>>(Q, sk1W, sk1b, nullptr, SK, nullptr, N);
    gather_kernel<64><<<cdiv(N * 16, 256), blk, 0, stream>>>(rowptr, csr, P, AGG, N);
    bnrelu_kernel<64><<<cdiv(N * 16, 256), blk, 0, stream>>>(AGG, bn1g, bn1b, bn1m, bn1v, SK, P, N);

    // ---- layer 2: 64 -> 32, residual = P @ sk2W + sk2b ----
    gemm_kernel<64, 32, true><<<cdiv(N, 256), blk, 0, stream>>>(P, W2, b2v, dinv, Q, AGG, N);
    gemm_kernel<64, 32, false><<<cdiv(N, 256), blk, 0, stream>>>(P, sk2W, sk2b, nullptr, SK, nullptr, N);
    gather_kernel<32><<<cdiv(N * 8, 256), blk, 0, stream>>>(rowptr, csr, Q, AGG, N);
    float* OUT2 = Q + (size_t)N * 32;
    bnrelu_kernel<32><<<cdiv(N * 8, 256), blk, 0, stream>>>(AGG, bn2g, bn2b, bn2m, bn2v, SK, OUT2, N);

    // ---- classifier + log_softmax ----
    classifier_kernel<<<cdiv(N, 256), blk, 0, stream>>>(OUT2, c1W, c1b, c2W, c2b, (float*)d_out, N);
}

// Round 3
// 268.373 us; speedup vs baseline: 9.4179x; 1.2925x over previous
//
#include <hip/hip_runtime.h>
#include <hip/hip_bf16.h>
#include <math.h>

// ---------------------------------------------------------------------------
// AdvancedGCN on MI355X — round 3:
//  * messages (H) stored bf16 -> gather traffic halved
//  * gather fuses self-loop + bias + BN + ReLU + residual (no AGG buffer)
//  * main+skip GEMMs fused into one dual-output kernel (X read once)
// ---------------------------------------------------------------------------

#define BN_EPS 1e-5f

static __device__ __forceinline__ float bf2f(unsigned int u16) {
    return __uint_as_float(u16 << 16);
}
static __device__ __forceinline__ unsigned short f2bf(float f) {
    unsigned int b = __float_as_uint(f);
    return (unsigned short)((b + 0x7FFFu + ((b >> 16) & 1u)) >> 16);
}
static __device__ __forceinline__ void unpack8(uint4 u, float* f) {
    f[0] = bf2f(u.x & 0xffffu); f[1] = bf2f(u.x >> 16);
    f[2] = bf2f(u.y & 0xffffu); f[3] = bf2f(u.y >> 16);
    f[4] = bf2f(u.z & 0xffffu); f[5] = bf2f(u.z >> 16);
    f[6] = bf2f(u.w & 0xffffu); f[7] = bf2f(u.w >> 16);
}

// --------------------------- CSR build kernels -----------------------------
__global__ void zero_counts_kernel(int* __restrict__ counts, int N) {
    int i = blockIdx.x * 256 + threadIdx.x;
    if (i < N) counts[i] = 0;
}

__global__ void hist_kernel(const int* __restrict__ dst, int* __restrict__ counts, int E) {
    int e = blockIdx.x * 256 + threadIdx.x;
    if (e < E) atomicAdd(&counts[dst[e]], 1);
}

__global__ void scan_block_kernel(const int* __restrict__ counts, int* __restrict__ excl,
                                  int* __restrict__ bsum, int N) {
    __shared__ int s[256];
    int tid = threadIdx.x;
    int i = blockIdx.x * 256 + tid;
    int v = (i < N) ? counts[i] : 0;
    s[tid] = v;
    __syncthreads();
#pragma unroll
    for (int off = 1; off < 256; off <<= 1) {
        int t = (tid >= off) ? s[tid - off] : 0;
        __syncthreads();
        s[tid] += t;
        __syncthreads();
    }
    if (i < N) excl[i] = s[tid] - v;
    if (tid == 255) bsum[blockIdx.x] = s[255];
}

__global__ void scan_sums_kernel(const int* __restrict__ bsum, int* __restrict__ boff, int nb) {
    __shared__ int s[256];
    int tid = threadIdx.x;
    int v = (tid < nb) ? bsum[tid] : 0;
    s[tid] = v;
    __syncthreads();
#pragma unroll
    for (int off = 1; off < 256; off <<= 1) {
        int t = (tid >= off) ? s[tid - off] : 0;
        __syncthreads();
        s[tid] += t;
        __syncthreads();
    }
    if (tid < nb) boff[tid] = s[tid] - v;
}

__global__ void scan_add_kernel(const int* __restrict__ excl, const int* __restrict__ boff,
                                const int* __restrict__ counts,
                                int* __restrict__ rowptr, int* __restrict__ cursor,
                                float* __restrict__ dinv, int N, int E) {
    int i = blockIdx.x * 256 + threadIdx.x;
    if (i < N) {
        int val = excl[i] + boff[blockIdx.x];
        rowptr[i] = val;
        cursor[i] = val;
        dinv[i]   = rsqrtf((float)counts[i] + 1.0f);
    }
    if (i == N) rowptr[N] = E;
}

__global__ void build_csr_kernel(const int* __restrict__ src, const int* __restrict__ dst,
                                 const float* __restrict__ dinv, int* __restrict__ cursor,
                                 int2* __restrict__ csr, int E) {
    int e = blockIdx.x * 256 + threadIdx.x;
    if (e >= E) return;
    int s = src[e], d = dst[e];
    int pos = atomicAdd(&cursor[d], 1);
    csr[pos] = make_int2(s, __float_as_int(dinv[s] * dinv[d]));
}

// ----------------------------- dual GEMM -----------------------------------
// H(bf16)[N,M1] = X @ Wc   (conv path, pre-bias, pre-norm)
// SK(f32)[N,M2] = X @ Wsk + skb  (skip path; M2 == 0 -> disabled)
template <int K, int M1, int M2>
__launch_bounds__(256)
__global__ void gemm_kernel(const float* __restrict__ X,
                            const float* __restrict__ Wc,
                            const float* __restrict__ Wsk, const float* __restrict__ skb,
                            unsigned short* __restrict__ H, float* __restrict__ SK, int N)
{
    constexpr int M    = M1 + M2;
    constexpr int CT   = 8;
    constexpr int COLT = M / CT;
    constexpr int RT   = 4;
    constexpr int TR   = (256 / COLT) * RT;
    constexpr int KC   = 32;
    constexpr int PADW = 4;

    __shared__ float Xs[KC][TR];
    __shared__ float Ws[KC][M + PADW];

    const int tid = threadIdx.x;
    const int i = tid / COLT;
    const int j = tid % COLT;
    const int r0 = blockIdx.x * TR;

    float acc[RT][CT];
#pragma unroll
    for (int r = 0; r < RT; ++r)
#pragma unroll
        for (int c = 0; c < CT; ++c) acc[r][c] = 0.0f;

    for (int k0 = 0; k0 < K; k0 += KC) {
        __syncthreads();
#pragma unroll
        for (int l = 0; l < TR / 32; ++l) {
            int f   = tid + 256 * l;
            int row = f >> 3;
            int kq  = f & 7;
            float4 v = make_float4(0.f, 0.f, 0.f, 0.f);
            if (r0 + row < N)
                v = *(const float4*)&X[(size_t)(r0 + row) * K + k0 + kq * 4];
            Xs[kq * 4 + 0][row] = v.x;
            Xs[kq * 4 + 1][row] = v.y;
            Xs[kq * 4 + 2][row] = v.z;
            Xs[kq * 4 + 3][row] = v.w;
        }
#pragma unroll
        for (int l = 0; l < M / 32; ++l) {
            int f   = tid + 256 * l;
            int kr  = f / (M / 4);
            int col = (f % (M / 4)) * 4;
            float4 v;
            if (M2 == 0 || col < M1)
                v = *(const float4*)&Wc[(size_t)(k0 + kr) * M1 + col];
            else
                v = *(const float4*)&Wsk[(size_t)(k0 + kr) * M2 + (col - M1)];
            *(float4*)&Ws[kr][col] = v;
        }
        __syncthreads();

#pragma unroll
        for (int kc = 0; kc < KC; ++kc) {
            float4 xa = *(const float4*)&Xs[kc][i * RT];
            float4 w0 = *(const float4*)&Ws[kc][j * CT];
            float4 w1 = *(const float4*)&Ws[kc][j * CT + 4];
            float xr[RT] = {xa.x, xa.y, xa.z, xa.w};
            float wc[CT] = {w0.x, w0.y, w0.z, w0.w, w1.x, w1.y, w1.z, w1.w};
#pragma unroll
            for (int r = 0; r < RT; ++r)
#pragma unroll
                for (int c = 0; c < CT; ++c)
                    acc[r][c] = fmaf(xr[r], wc[c], acc[r][c]);
        }
    }

    const int col = j * CT;   // uniform per thread; entirely conv or entirely skip
    if (M2 == 0 || col < M1) {
#pragma unroll
        for (int r = 0; r < RT; ++r) {
            int row = r0 + i * RT + r;
            if (row >= N) continue;
            uint4 u;
            u.x = (unsigned)f2bf(acc[r][0]) | ((unsigned)f2bf(acc[r][1]) << 16);
            u.y = (unsigned)f2bf(acc[r][2]) | ((unsigned)f2bf(acc[r][3]) << 16);
            u.z = (unsigned)f2bf(acc[r][4]) | ((unsigned)f2bf(acc[r][5]) << 16);
            u.w = (unsigned)f2bf(acc[r][6]) | ((unsigned)f2bf(acc[r][7]) << 16);
            *(uint4*)&H[(size_t)row * M1 + col] = u;
        }
    } else {
        const int sc = col - M1;
        const float4 sb0 = *(const float4*)&skb[sc];
        const float4 sb1 = *(const float4*)&skb[sc + 4];
#pragma unroll
        for (int r = 0; r < RT; ++r) {
            int row = r0 + i * RT + r;
            if (row >= N) continue;
            size_t base = (size_t)row * M2 + sc;
            float4 s0 = make_float4(acc[r][0] + sb0.x, acc[r][1] + sb0.y,
                                    acc[r][2] + sb0.z, acc[r][3] + sb0.w);
            float4 s1 = make_float4(acc[r][4] + sb1.x, acc[r][5] + sb1.y,
                                    acc[r][6] + sb1.z, acc[r][7] + sb1.w);
            *(float4*)&SK[base]     = s0;
            *(float4*)&SK[base + 4] = s1;
        }
    }
}

// ------------------ fused gather + self + BN + ReLU + residual -------------
// sum = Σ_{edges} H[src]*w + H[n]*dinv[n]^2 ;  out = relu((sum+bias-m)*g/√(v+eps)+b) + res
template <int M>
__launch_bounds__(256)
__global__ void gather_bn_kernel(const int* __restrict__ rowptr, const int2* __restrict__ csr,
                                 const unsigned short* __restrict__ H,
                                 const float* __restrict__ dinv,
                                 const float* __restrict__ bias,
                                 const float* __restrict__ g, const float* __restrict__ b,
                                 const float* __restrict__ m, const float* __restrict__ v,
                                 const float* __restrict__ res, float* __restrict__ out, int N)
{
    constexpr int TPN = M / 8;
    int gid = blockIdx.x * 256 + threadIdx.x;
    int n = gid / TPN;
    if (n >= N) return;
    const int c = (gid % TPN) * 8;

    // fold BN: out_pre = sum * s + o
    float s[8], o[8];
#pragma unroll
    for (int q = 0; q < 2; ++q) {
        float4 gv = *(const float4*)&g[c + q * 4];
        float4 bv = *(const float4*)&b[c + q * 4];
        float4 mv = *(const float4*)&m[c + q * 4];
        float4 vv = *(const float4*)&v[c + q * 4];
        float4 iv = *(const float4*)&bias[c + q * 4];
        float sv[4] = {gv.x * rsqrtf(vv.x + BN_EPS), gv.y * rsqrtf(vv.y + BN_EPS),
                       gv.z * rsqrtf(vv.z + BN_EPS), gv.w * rsqrtf(vv.w + BN_EPS)};
        float bb[4] = {bv.x, bv.y, bv.z, bv.w};
        float mm[4] = {mv.x, mv.y, mv.z, mv.w};
        float ii[4] = {iv.x, iv.y, iv.z, iv.w};
#pragma unroll
        for (int q2 = 0; q2 < 4; ++q2) {
            s[q * 4 + q2] = sv[q2];
            o[q * 4 + q2] = (ii[q2] - mm[q2]) * sv[q2] + bb[q2];
        }
    }

    // self-loop term
    float d  = dinv[n];
    float d2 = d * d;
    float acc[8], hf[8];
    uint4 hs = *(const uint4*)&H[(size_t)n * M + c];
    unpack8(hs, hf);
#pragma unroll
    for (int k = 0; k < 8; ++k) acc[k] = hf[k] * d2;

    // neighbors (2-unrolled)
    int p   = rowptr[n];
    int end = rowptr[n + 1];
    for (; p + 1 < end; p += 2) {
        int2 e0 = csr[p];
        int2 e1 = csr[p + 1];
        uint4 h0 = *(const uint4*)&H[(size_t)e0.x * M + c];
        uint4 h1 = *(const uint4*)&H[(size_t)e1.x * M + c];
        float w0 = __int_as_float(e0.y);
        float w1 = __int_as_float(e1.y);
        float f0[8], f1[8];
        unpack8(h0, f0);
        unpack8(h1, f1);
#pragma unroll
        for (int k = 0; k < 8; ++k) acc[k] = fmaf(f0[k], w0, acc[k]);
#pragma unroll
        for (int k = 0; k < 8; ++k) acc[k] = fmaf(f1[k], w1, acc[k]);
    }
    if (p < end) {
        int2 e0 = csr[p];
        uint4 h0 = *(const uint4*)&H[(size_t)e0.x * M + c];
        float w0 = __int_as_float(e0.y);
        float f0[8];
        unpack8(h0, f0);
#pragma unroll
        for (int k = 0; k < 8; ++k) acc[k] = fmaf(f0[k], w0, acc[k]);
    }

    // BN + ReLU + residual
    float4 r0 = *(const float4*)&res[(size_t)n * M + c];
    float4 r1 = *(const float4*)&res[(size_t)n * M + c + 4];
    float rr[8] = {r0.x, r0.y, r0.z, r0.w, r1.x, r1.y, r1.z, r1.w};
    float outv[8];
#pragma unroll
    for (int k = 0; k < 8; ++k)
        outv[k] = fmaxf(fmaf(acc[k], s[k], o[k]), 0.f) + rr[k];
    *(float4*)&out[(size_t)n * M + c]     = make_float4(outv[0], outv[1], outv[2], outv[3]);
    *(float4*)&out[(size_t)n * M + c + 4] = make_float4(outv[4], outv[5], outv[6], outv[7]);
}

// ------------------------- classifier + log_softmax ------------------------
__global__ void classifier_kernel(const float* __restrict__ H2,
                                  const float* __restrict__ W1, const float* __restrict__ B1,
                                  const float* __restrict__ W2, const float* __restrict__ B2,
                                  float* __restrict__ out, int N)
{
    __shared__ float w1s[32 * 16];
    __shared__ float b1s[16];
    __shared__ float w2s[16 * 2];
    __shared__ float b2s[2];
    int tid = threadIdx.x;
    for (int t = tid; t < 512; t += 256) w1s[t] = W1[t];
    if (tid < 16) b1s[tid] = B1[tid];
    if (tid < 32) w2s[tid] = W2[tid];
    if (tid < 2)  b2s[tid] = B2[tid];
    __syncthreads();

    int n = blockIdx.x * 256 + tid;
    if (n >= N) return;

    float x[32];
#pragma unroll
    for (int q = 0; q < 8; ++q) {
        float4 v = *(const float4*)&H2[(size_t)n * 32 + q * 4];
        x[q * 4 + 0] = v.x; x[q * 4 + 1] = v.y; x[q * 4 + 2] = v.z; x[q * 4 + 3] = v.w;
    }
    float h[16];
#pragma unroll
    for (int jj = 0; jj < 16; ++jj) h[jj] = b1s[jj];
#pragma unroll
    for (int k = 0; k < 32; ++k)
#pragma unroll
        for (int jj = 0; jj < 16; ++jj)
            h[jj] = fmaf(x[k], w1s[k * 16 + jj], h[jj]);

    float z0 = b2s[0], z1 = b2s[1];
#pragma unroll
    for (int jj = 0; jj < 16; ++jj) {
        float r = fmaxf(h[jj], 0.f);
        z0 = fmaf(r, w2s[jj * 2 + 0], z0);
        z1 = fmaf(r, w2s[jj * 2 + 1], z1);
    }
    float mx  = fmaxf(z0, z1);
    float lse = mx + logf(expf(z0 - mx) + expf(z1 - mx));
    out[(size_t)n * 2 + 0] = z0 - lse;
    out[(size_t)n * 2 + 1] = z1 - lse;
}

// ------------------------------- launch ------------------------------------
extern "C" void kernel_launch(void* const* d_in, const int* in_sizes, int n_in,
                              void* d_out, int out_size, void* d_ws, size_t ws_size,
                              hipStream_t stream)
{
    const float* x    = (const float*)d_in[0];
    const int*   edge = (const int*)d_in[1];
    const float* W0   = (const float*)d_in[2];
    const float* b0v  = (const float*)d_in[3];
    const float* bn0g = (const float*)d_in[4];
    const float* bn0b = (const float*)d_in[5];
    const float* bn0m = (const float*)d_in[6];
    const float* bn0v = (const float*)d_in[7];
    const float* W1   = (const float*)d_in[8];
    const float* b1v  = (const float*)d_in[9];
    const float* bn1g = (const float*)d_in[10];
    const float* bn1b = (const float*)d_in[11];
    const float* bn1m = (const float*)d_in[12];
    const float* bn1v = (const float*)d_in[13];
    const float* sk1W = (const float*)d_in[14];
    const float* sk1b = (const float*)d_in[15];
    const float* W2   = (const float*)d_in[16];
    const float* b2v  = (const float*)d_in[17];
    const float* bn2g = (const float*)d_in[18];
    const float* bn2b = (const float*)d_in[19];
    const float* bn2m = (const float*)d_in[20];
    const float* bn2v = (const float*)d_in[21];
    const float* sk2W = (const float*)d_in[22];
    const float* sk2b = (const float*)d_in[23];
    const float* c1W  = (const float*)d_in[24];
    const float* c1b  = (const float*)d_in[25];
    const float* c2W  = (const float*)d_in[26];
    const float* c2b  = (const float*)d_in[27];

    const int N = in_sizes[0] / 128;
    const int E = in_sizes[1] / 2;
    const int* src = edge;
    const int* dst = edge + E;

    char*  ws  = (char*)d_ws;
    size_t off = 0;
    auto alloc = [&](size_t bytes) -> char* {
        char* p = ws + off;
        off += (bytes + 255) & ~(size_t)255;
        return p;
    };
    float*          dinv   = (float*)alloc((size_t)N * 4);
    int*            counts = (int*)  alloc((size_t)N * 4);
    int*            excl   = (int*)  alloc((size_t)N * 4);
    int*            rowptr = (int*)  alloc((size_t)(N + 1) * 4);
    int*            cursor = (int*)  alloc((size_t)N * 4);
    int*            bsum   = (int*)  alloc(256 * 4);
    int*            boff   = (int*)  alloc(256 * 4);
    int2*           csr    = (int2*) alloc((size_t)E * 8);
    unsigned short* Hb     = (unsigned short*)alloc((size_t)N * 128 * 2);
    float*          SK     = (float*)alloc((size_t)N * 64 * 4);
    float*          Q0     = (float*)alloc((size_t)N * 128 * 4);
    float*          P1     = (float*)alloc((size_t)N * 64 * 4);
    float*          O2     = (float*)alloc((size_t)N * 32 * 4);
    (void)ws_size; (void)n_in; (void)out_size;

    dim3 blk(256);
    auto cdiv = [](int a, int b) { return (a + b - 1) / b; };
    const int nbN = cdiv(N, 256);

    // ---- CSR build (by dst) + dinv ----
    zero_counts_kernel<<<nbN, blk, 0, stream>>>(counts, N);
    hist_kernel<<<cdiv(E, 256), blk, 0, stream>>>(dst, counts, E);
    scan_block_kernel<<<nbN, blk, 0, stream>>>(counts, excl, bsum, N);
    scan_sums_kernel<<<1, blk, 0, stream>>>(bsum, boff, nbN);
    scan_add_kernel<<<cdiv(N + 1, 256), blk, 0, stream>>>(excl, boff, counts, rowptr, cursor, dinv, N, E);
    build_csr_kernel<<<cdiv(E, 256), blk, 0, stream>>>(src, dst, dinv, cursor, csr, E);

    // ---- layer 0: 128 -> 128, residual = x ----
    gemm_kernel<128, 128, 0><<<cdiv(N, 64), blk, 0, stream>>>(x, W0, nullptr, nullptr, Hb, nullptr, N);
    gather_bn_kernel<128><<<cdiv(N * 16, 256), blk, 0, stream>>>(
        rowptr, csr, Hb, dinv, b0v, bn0g, bn0b, bn0m, bn0v, x, Q0, N);

    // ---- layer 1: 128 -> 64, skip fused ----
    gemm_kernel<128, 64, 64><<<cdiv(N, 64), blk, 0, stream>>>(Q0, W1, sk1W, sk1b, Hb, SK, N);
    gather_bn_kernel<64><<<cdiv(N * 8, 256), blk, 0, stream>>>(
        rowptr, csr, Hb, dinv, b1v, bn1g, bn1b, bn1m, bn1v, SK, P1, N);

    // ---- layer 2: 64 -> 32, skip fused ----
    gemm_kernel<64, 32, 32><<<cdiv(N, 128), blk, 0, stream>>>(P1, W2, sk2W, sk2b, Hb, SK, N);
    gather_bn_kernel<32><<<cdiv(N * 4, 256), blk, 0, stream>>>(
        rowptr, csr, Hb, dinv, b2v, bn2g, bn2b, bn2m, bn2v, SK, O2, N);

    // ---- classifier + log_softmax ----
    classifier_kernel<<<cdiv(N, 256), blk, 0, stream>>>(O2, c1W, c1b, c2W, c2b, (float*)d_out, N);
}

// Round 4
// 232.006 us; speedup vs baseline: 10.8942x; 1.1567x over previous
//
#include <hip/hip_runtime.h>
#include <hip/hip_bf16.h>
#include <math.h>

// ---------------------------------------------------------------------------
// AdvancedGCN on MI355X — round 4:
//  * CSR build: rank computed in the hist pass (one atomic-return pass total),
//    fill pass is atomic-free; csr stores src only (4B) — weight recomputed
//    in gather from L2-resident dinv.
//  * scan_sums merged into scan_add; counts zeroed via hipMemsetAsync.
//  * gather unrolled x4 for memory-level parallelism.
// ---------------------------------------------------------------------------

#define BN_EPS 1e-5f

static __device__ __forceinline__ float bf2f(unsigned int u16) {
    return __uint_as_float(u16 << 16);
}
static __device__ __forceinline__ unsigned short f2bf(float f) {
    unsigned int b = __float_as_uint(f);
    return (unsigned short)((b + 0x7FFFu + ((b >> 16) & 1u)) >> 16);
}
static __device__ __forceinline__ void unpack8(uint4 u, float* f) {
    f[0] = bf2f(u.x & 0xffffu); f[1] = bf2f(u.x >> 16);
    f[2] = bf2f(u.y & 0xffffu); f[3] = bf2f(u.y >> 16);
    f[4] = bf2f(u.z & 0xffffu); f[5] = bf2f(u.z >> 16);
    f[6] = bf2f(u.w & 0xffffu); f[7] = bf2f(u.w >> 16);
}

// --------------------------- CSR build kernels -----------------------------
// counts must be zeroed before this (hipMemsetAsync).
// rank[e] = position of edge e within its dst bucket; counts -> in-degrees.
__global__ void rank_hist_kernel(const int* __restrict__ dst, int* __restrict__ counts,
                                 int* __restrict__ rank, int E) {
    int e = blockIdx.x * 256 + threadIdx.x;
    if (e < E) rank[e] = atomicAdd(&counts[dst[e]], 1);
}

// block-level inclusive scan -> per-element exclusive + block sums
__global__ void scan_block_kernel(const int* __restrict__ counts, int* __restrict__ excl,
                                  int* __restrict__ bsum, int N) {
    __shared__ int s[256];
    int tid = threadIdx.x;
    int i = blockIdx.x * 256 + tid;
    int v = (i < N) ? counts[i] : 0;
    s[tid] = v;
    __syncthreads();
#pragma unroll
    for (int off = 1; off < 256; off <<= 1) {
        int t = (tid >= off) ? s[tid - off] : 0;
        __syncthreads();
        s[tid] += t;
        __syncthreads();
    }
    if (i < N) excl[i] = s[tid] - v;
    if (tid == 255) bsum[blockIdx.x] = s[255];
}

// finalize: each block scans the (<=256) block sums in LDS itself, then
// rowptr[i] = excl[i] + excl_block_sum; dinv = rsqrt(indeg + 1).
__global__ void scan_add_kernel(const int* __restrict__ excl, const int* __restrict__ bsum,
                                const int* __restrict__ counts,
                                int* __restrict__ rowptr, float* __restrict__ dinv,
                                int nb, int N, int E) {
    __shared__ int sb[256];
    int tid = threadIdx.x;
    int v = (tid < nb) ? bsum[tid] : 0;
    sb[tid] = v;
    __syncthreads();
#pragma unroll
    for (int off = 1; off < 256; off <<= 1) {
        int t = (tid >= off) ? sb[tid - off] : 0;
        __syncthreads();
        sb[tid] += t;
        __syncthreads();
    }
    int eb = sb[blockIdx.x] - ((blockIdx.x < nb) ? bsum[blockIdx.x] : 0);  // exclusive
    int i = blockIdx.x * 256 + tid;
    if (i < N) {
        rowptr[i] = excl[i] + eb;
        dinv[i]   = rsqrtf((float)counts[i] + 1.0f);
    }
    if (i == N) rowptr[N] = E;
}

// atomic-free fill: csr[rowptr[d] + rank[e]] = src[e]
__global__ void fill_csr_kernel(const int* __restrict__ src, const int* __restrict__ dst,
                                const int* __restrict__ rank, const int* __restrict__ rowptr,
                                int* __restrict__ csr, int E) {
    int e = blockIdx.x * 256 + threadIdx.x;
    if (e >= E) return;
    csr[rowptr[dst[e]] + rank[e]] = src[e];
}

// ----------------------------- dual GEMM -----------------------------------
// H(bf16)[N,M1] = X @ Wc   (conv path, pre-bias, pre-norm)
// SK(f32)[N,M2] = X @ Wsk + skb  (skip path; M2 == 0 -> disabled)
template <int K, int M1, int M2>
__launch_bounds__(256)
__global__ void gemm_kernel(const float* __restrict__ X,
                            const float* __restrict__ Wc,
                            const float* __restrict__ Wsk, const float* __restrict__ skb,
                            unsigned short* __restrict__ H, float* __restrict__ SK, int N)
{
    constexpr int M    = M1 + M2;
    constexpr int CT   = 8;
    constexpr int COLT = M / CT;
    constexpr int RT   = 4;
    constexpr int TR   = (256 / COLT) * RT;
    constexpr int KC   = 32;
    constexpr int PADW = 4;

    __shared__ float Xs[KC][TR];
    __shared__ float Ws[KC][M + PADW];

    const int tid = threadIdx.x;
    const int i = tid / COLT;
    const int j = tid % COLT;
    const int r0 = blockIdx.x * TR;

    float acc[RT][CT];
#pragma unroll
    for (int r = 0; r < RT; ++r)
#pragma unroll
        for (int c = 0; c < CT; ++c) acc[r][c] = 0.0f;

    for (int k0 = 0; k0 < K; k0 += KC) {
        __syncthreads();
#pragma unroll
        for (int l = 0; l < TR / 32; ++l) {
            int f   = tid + 256 * l;
            int row = f >> 3;
            int kq  = f & 7;
            float4 v = make_float4(0.f, 0.f, 0.f, 0.f);
            if (r0 + row < N)
                v = *(const float4*)&X[(size_t)(r0 + row) * K + k0 + kq * 4];
            Xs[kq * 4 + 0][row] = v.x;
            Xs[kq * 4 + 1][row] = v.y;
            Xs[kq * 4 + 2][row] = v.z;
            Xs[kq * 4 + 3][row] = v.w;
        }
#pragma unroll
        for (int l = 0; l < M / 32; ++l) {
            int f   = tid + 256 * l;
            int kr  = f / (M / 4);
            int col = (f % (M / 4)) * 4;
            float4 v;
            if (M2 == 0 || col < M1)
                v = *(const float4*)&Wc[(size_t)(k0 + kr) * M1 + col];
            else
                v = *(const float4*)&Wsk[(size_t)(k0 + kr) * M2 + (col - M1)];
            *(float4*)&Ws[kr][col] = v;
        }
        __syncthreads();

#pragma unroll
        for (int kc = 0; kc < KC; ++kc) {
            float4 xa = *(const float4*)&Xs[kc][i * RT];
            float4 w0 = *(const float4*)&Ws[kc][j * CT];
            float4 w1 = *(const float4*)&Ws[kc][j * CT + 4];
            float xr[RT] = {xa.x, xa.y, xa.z, xa.w};
            float wc[CT] = {w0.x, w0.y, w0.z, w0.w, w1.x, w1.y, w1.z, w1.w};
#pragma unroll
            for (int r = 0; r < RT; ++r)
#pragma unroll
                for (int c = 0; c < CT; ++c)
                    acc[r][c] = fmaf(xr[r], wc[c], acc[r][c]);
        }
    }

    const int col = j * CT;   // uniform per thread; entirely conv or entirely skip
    if (M2 == 0 || col < M1) {
#pragma unroll
        for (int r = 0; r < RT; ++r) {
            int row = r0 + i * RT + r;
            if (row >= N) continue;
            uint4 u;
            u.x = (unsigned)f2bf(acc[r][0]) | ((unsigned)f2bf(acc[r][1]) << 16);
            u.y = (unsigned)f2bf(acc[r][2]) | ((unsigned)f2bf(acc[r][3]) << 16);
            u.z = (unsigned)f2bf(acc[r][4]) | ((unsigned)f2bf(acc[r][5]) << 16);
            u.w = (unsigned)f2bf(acc[r][6]) | ((unsigned)f2bf(acc[r][7]) << 16);
            *(uint4*)&H[(size_t)row * M1 + col] = u;
        }
    } else {
        const int sc = col - M1;
        const float4 sb0 = *(const float4*)&skb[sc];
        const float4 sb1 = *(const float4*)&skb[sc + 4];
#pragma unroll
        for (int r = 0; r < RT; ++r) {
            int row = r0 + i * RT + r;
            if (row >= N) continue;
            size_t base = (size_t)row * M2 + sc;
            float4 s0 = make_float4(acc[r][0] + sb0.x, acc[r][1] + sb0.y,
                                    acc[r][2] + sb0.z, acc[r][3] + sb0.w);
            float4 s1 = make_float4(acc[r][4] + sb1.x, acc[r][5] + sb1.y,
                                    acc[r][6] + sb1.z, acc[r][7] + sb1.w);
            *(float4*)&SK[base]     = s0;
            *(float4*)&SK[base + 4] = s1;
        }
    }
}

// ------------------ fused gather + self + BN + ReLU + residual -------------
// sum = Σ_{edges} H[src]*dinv[src]*dinv[n] + H[n]*dinv[n]^2
// out = relu((sum+bias-m)*g/√(v+eps)+b) + res
template <int M>
__launch_bounds__(256)
__global__ void gather_bn_kernel(const int* __restrict__ rowptr, const int* __restrict__ csr,
                                 const unsigned short* __restrict__ H,
                                 const float* __restrict__ dinv,
                                 const float* __restrict__ bias,
                                 const float* __restrict__ g, const float* __restrict__ b,
                                 const float* __restrict__ m, const float* __restrict__ v,
                                 const float* __restrict__ res, float* __restrict__ out, int N)
{
    constexpr int TPN = M / 8;
    int gid = blockIdx.x * 256 + threadIdx.x;
    int n = gid / TPN;
    if (n >= N) return;
    const int c = (gid % TPN) * 8;

    // fold BN: out_pre = sum * s + o
    float s[8], o[8];
#pragma unroll
    for (int q = 0; q < 2; ++q) {
        float4 gv = *(const float4*)&g[c + q * 4];
        float4 bv = *(const float4*)&b[c + q * 4];
        float4 mv = *(const float4*)&m[c + q * 4];
        float4 vv = *(const float4*)&v[c + q * 4];
        float4 iv = *(const float4*)&bias[c + q * 4];
        float sv[4] = {gv.x * rsqrtf(vv.x + BN_EPS), gv.y * rsqrtf(vv.y + BN_EPS),
                       gv.z * rsqrtf(vv.z + BN_EPS), gv.w * rsqrtf(vv.w + BN_EPS)};
        float bb[4] = {bv.x, bv.y, bv.z, bv.w};
        float mm[4] = {mv.x, mv.y, mv.z, mv.w};
        float ii[4] = {iv.x, iv.y, iv.z, iv.w};
#pragma unroll
        for (int q2 = 0; q2 < 4; ++q2) {
            s[q * 4 + q2] = sv[q2];
            o[q * 4 + q2] = (ii[q2] - mm[q2]) * sv[q2] + bb[q2];
        }
    }

    const float dn = dinv[n];

    // self-loop term
    float acc[8], hf[8];
    uint4 hs = *(const uint4*)&H[(size_t)n * M + c];
    unpack8(hs, hf);
    const float d2 = dn * dn;
#pragma unroll
    for (int k = 0; k < 8; ++k) acc[k] = hf[k] * d2;

    // neighbors (4-unrolled for MLP)
    int p   = rowptr[n];
    int end = rowptr[n + 1];
    for (; p + 3 < end; p += 4) {
        int s0 = csr[p], s1 = csr[p + 1], s2 = csr[p + 2], s3 = csr[p + 3];
        uint4 h0 = *(const uint4*)&H[(size_t)s0 * M + c];
        uint4 h1 = *(const uint4*)&H[(size_t)s1 * M + c];
        uint4 h2 = *(const uint4*)&H[(size_t)s2 * M + c];
        uint4 h3 = *(const uint4*)&H[(size_t)s3 * M + c];
        float w0 = dinv[s0] * dn, w1 = dinv[s1] * dn;
        float w2 = dinv[s2] * dn, w3 = dinv[s3] * dn;
        float f0[8], f1[8], f2[8], f3[8];
        unpack8(h0, f0); unpack8(h1, f1); unpack8(h2, f2); unpack8(h3, f3);
#pragma unroll
        for (int k = 0; k < 8; ++k) acc[k] = fmaf(f0[k], w0, acc[k]);
#pragma unroll
        for (int k = 0; k < 8; ++k) acc[k] = fmaf(f1[k], w1, acc[k]);
#pragma unroll
        for (int k = 0; k < 8; ++k) acc[k] = fmaf(f2[k], w2, acc[k]);
#pragma unroll
        for (int k = 0; k < 8; ++k) acc[k] = fmaf(f3[k], w3, acc[k]);
    }
    for (; p < end; ++p) {
        int s0 = csr[p];
        uint4 h0 = *(const uint4*)&H[(size_t)s0 * M + c];
        float w0 = dinv[s0] * dn;
        float f0[8];
        unpack8(h0, f0);
#pragma unroll
        for (int k = 0; k < 8; ++k) acc[k] = fmaf(f0[k], w0, acc[k]);
    }

    // BN + ReLU + residual
    float4 r0 = *(const float4*)&res[(size_t)n * M + c];
    float4 r1 = *(const float4*)&res[(size_t)n * M + c + 4];
    float rr[8] = {r0.x, r0.y, r0.z, r0.w, r1.x, r1.y, r1.z, r1.w};
    float outv[8];
#pragma unroll
    for (int k = 0; k < 8; ++k)
        outv[k] = fmaxf(fmaf(acc[k], s[k], o[k]), 0.f) + rr[k];
    *(float4*)&out[(size_t)n * M + c]     = make_float4(outv[0], outv[1], outv[2], outv[3]);
    *(float4*)&out[(size_t)n * M + c + 4] = make_float4(outv[4], outv[5], outv[6], outv[7]);
}

// ------------------------- classifier + log_softmax ------------------------
__global__ void classifier_kernel(const float* __restrict__ H2,
                                  const float* __restrict__ W1, const float* __restrict__ B1,
                                  const float* __restrict__ W2, const float* __restrict__ B2,
                                  float* __restrict__ out, int N)
{
    __shared__ float w1s[32 * 16];
    __shared__ float b1s[16];
    __shared__ float w2s[16 * 2];
    __shared__ float b2s[2];
    int tid = threadIdx.x;
    for (int t = tid; t < 512; t += 256) w1s[t] = W1[t];
    if (tid < 16) b1s[tid] = B1[tid];
    if (tid < 32) w2s[tid] = W2[tid];
    if (tid < 2)  b2s[tid] = B2[tid];
    __syncthreads();

    int n = blockIdx.x * 256 + tid;
    if (n >= N) return;

    float x[32];
#pragma unroll
    for (int q = 0; q < 8; ++q) {
        float4 v = *(const float4*)&H2[(size_t)n * 32 + q * 4];
        x[q * 4 + 0] = v.x; x[q * 4 + 1] = v.y; x[q * 4 + 2] = v.z; x[q * 4 + 3] = v.w;
    }
    float h[16];
#pragma unroll
    for (int jj = 0; jj < 16; ++jj) h[jj] = b1s[jj];
#pragma unroll
    for (int k = 0; k < 32; ++k)
#pragma unroll
        for (int jj = 0; jj < 16; ++jj)
            h[jj] = fmaf(x[k], w1s[k * 16 + jj], h[jj]);

    float z0 = b2s[0], z1 = b2s[1];
#pragma unroll
    for (int jj = 0; jj < 16; ++jj) {
        float r = fmaxf(h[jj], 0.f);
        z0 = fmaf(r, w2s[jj * 2 + 0], z0);
        z1 = fmaf(r, w2s[jj * 2 + 1], z1);
    }
    float mx  = fmaxf(z0, z1);
    float lse = mx + logf(expf(z0 - mx) + expf(z1 - mx));
    out[(size_t)n * 2 + 0] = z0 - lse;
    out[(size_t)n * 2 + 1] = z1 - lse;
}

// ------------------------------- launch ------------------------------------
extern "C" void kernel_launch(void* const* d_in, const int* in_sizes, int n_in,
                              void* d_out, int out_size, void* d_ws, size_t ws_size,
                              hipStream_t stream)
{
    const float* x    = (const float*)d_in[0];
    const int*   edge = (const int*)d_in[1];
    const float* W0   = (const float*)d_in[2];
    const float* b0v  = (const float*)d_in[3];
    const float* bn0g = (const float*)d_in[4];
    const float* bn0b = (const float*)d_in[5];
    const float* bn0m = (const float*)d_in[6];
    const float* bn0v = (const float*)d_in[7];
    const float* W1   = (const float*)d_in[8];
    const float* b1v  = (const float*)d_in[9];
    const float* bn1g = (const float*)d_in[10];
    const float* bn1b = (const float*)d_in[11];
    const float* bn1m = (const float*)d_in[12];
    const float* bn1v = (const float*)d_in[13];
    const float* sk1W = (const float*)d_in[14];
    const float* sk1b = (const float*)d_in[15];
    const float* W2   = (const float*)d_in[16];
    const float* b2v  = (const float*)d_in[17];
    const float* bn2g = (const float*)d_in[18];
    const float* bn2b = (const float*)d_in[19];
    const float* bn2m = (const float*)d_in[20];
    const float* bn2v = (const float*)d_in[21];
    const float* sk2W = (const float*)d_in[22];
    const float* sk2b = (const float*)d_in[23];
    const float* c1W  = (const float*)d_in[24];
    const float* c1b  = (const float*)d_in[25];
    const float* c2W  = (const float*)d_in[26];
    const float* c2b  = (const float*)d_in[27];

    const int N = in_sizes[0] / 128;
    const int E = in_sizes[1] / 2;
    const int* src = edge;
    const int* dst = edge + E;

    char*  ws  = (char*)d_ws;
    size_t off = 0;
    auto alloc = [&](size_t bytes) -> char* {
        char* p = ws + off;
        off += (bytes + 255) & ~(size_t)255;
        return p;
    };
    float*          dinv   = (float*)alloc((size_t)N * 4);
    int*            counts = (int*)  alloc((size_t)N * 4);
    int*            excl   = (int*)  alloc((size_t)N * 4);
    int*            rowptr = (int*)  alloc((size_t)(N + 1) * 4);
    int*            bsum   = (int*)  alloc(256 * 4);
    int*            rank   = (int*)  alloc((size_t)E * 4);
    int*            csr    = (int*)  alloc((size_t)E * 4);
    unsigned short* Hb     = (unsigned short*)alloc((size_t)N * 128 * 2);
    float*          SK     = (float*)alloc((size_t)N * 64 * 4);
    float*          Q0     = (float*)alloc((size_t)N * 128 * 4);
    float*          P1     = (float*)alloc((size_t)N * 64 * 4);
    float*          O2     = (float*)alloc((size_t)N * 32 * 4);
    (void)ws_size; (void)n_in; (void)out_size;

    dim3 blk(256);
    auto cdiv = [](int a, int b) { return (a + b - 1) / b; };
    const int nbN = cdiv(N, 256);

    // ---- CSR build (by dst) + dinv ----
    hipMemsetAsync(counts, 0, (size_t)N * 4, stream);
    rank_hist_kernel<<<cdiv(E, 256), blk, 0, stream>>>(dst, counts, rank, E);
    scan_block_kernel<<<nbN, blk, 0, stream>>>(counts, excl, bsum, N);
    scan_add_kernel<<<cdiv(N + 1, 256), blk, 0, stream>>>(excl, bsum, counts, rowptr, dinv, nbN, N, E);
    fill_csr_kernel<<<cdiv(E, 256), blk, 0, stream>>>(src, dst, rank, rowptr, csr, E);

    // ---- layer 0: 128 -> 128, residual = x ----
    gemm_kernel<128, 128, 0><<<cdiv(N, 64), blk, 0, stream>>>(x, W0, nullptr, nullptr, Hb, nullptr, N);
    gather_bn_kernel<128><<<cdiv(N * 16, 256), blk, 0, stream>>>(
        rowptr, csr, Hb, dinv, b0v, bn0g, bn0b, bn0m, bn0v, x, Q0, N);

    // ---- layer 1: 128 -> 64, skip fused ----
    gemm_kernel<128, 64, 64><<<cdiv(N, 64), blk, 0, stream>>>(Q0, W1, sk1W, sk1b, Hb, SK, N);
    gather_bn_kernel<64><<<cdiv(N * 8, 256), blk, 0, stream>>>(
        rowptr, csr, Hb, dinv, b1v, bn1g, bn1b, bn1m, bn1v, SK, P1, N);

    // ---- layer 2: 64 -> 32, skip fused ----
    gemm_kernel<64, 32, 32><<<cdiv(N, 128), blk, 0, stream>>>(P1, W2, sk2W, sk2b, Hb, SK, N);
    gather_bn_kernel<32><<<cdiv(N * 4, 256), blk, 0, stream>>>(
        rowptr, csr, Hb, dinv, b2v, bn2g, bn2b, bn2m, bn2v, SK, O2, N);

    // ---- classifier + log_softmax ----
    classifier_kernel<<<cdiv(N, 256), blk, 0, stream>>>(O2, c1W, c1b, c2W, c2b, (float*)d_out, N);
}